// Round 8
// baseline (105.370 us; speedup 1.0000x reference)
//
#include <hip/hip_runtime.h>
#include <math.h>

#define BATCH 4096
#define NODES 256
#define FDIM  128
#define HID   16

typedef __attribute__((ext_vector_type(8))) short short8;  // 8 bf16 (4 VGPRs)
typedef __attribute__((ext_vector_type(4))) float f32x4;   // MFMA C/D frag

// round-to-nearest-even bf16
__device__ __forceinline__ short bf_rn(float x) {
    const unsigned u = __float_as_uint(x);
    return (short)((u + 0x7FFF + ((u >> 16) & 1)) >> 16);
}
__device__ __forceinline__ float bf_back(short s) {
    return __uint_as_float(((unsigned)(unsigned short)s) << 16);
}
// x ~= hi + lo, hi = RN(x), lo = RN(residual): residual error ~2^-18 relative.
__device__ __forceinline__ void split8(float4 v0, float4 v1,
                                       short8& hi, short8& lo) {
    float v[8] = {v0.x, v0.y, v0.z, v0.w, v1.x, v1.y, v1.z, v1.w};
    #pragma unroll
    for (int j = 0; j < 8; ++j) {
        const short h = bf_rn(v[j]);
        hi[j] = h;
        lo[j] = bf_rn(v[j] - bf_back(h));
    }
}

// One block per batch element b; 4 waves; wave w owns rows 64w..64w+63 as
// 4 M-tiles of 16. Per-block GEMM [256x128]x[128x16] via mfma_16x16x32_bf16.
// Weights: single RN-bf16 B-fragments (16 VGPRs, loaded once); x split hi+lo
// -> 2 MFMAs per tile (x_hi*w + x_lo*w). Weight-rounding error ~2^-9 rel on e
// -> ~1e-3 on probs, well under the 1.9e-2 threshold.
// Diagnosis driving this round: R4's FETCH=290MB (<537MB input) shows ~250MB
// is L3-resident across replays -> true floor ~50-60us, we're latency-bound.
// Fix = TLP: __launch_bounds__(256,3) caps VGPR at ~85 (empirical cap=256/w)
// -> 6 waves/SIMD instead of 4. ra loads batched 2 M-tiles at a time to keep
// peak live regs ~75 (no spill; spill signature = WRITE_SIZE >> 6MB).
__launch_bounds__(256, 3)
__global__ void mta_kernel(const float* __restrict__ x,
                           const float* __restrict__ a1,
                           const float* __restrict__ a2,
                           const float* __restrict__ adj,
                           const int*  __restrict__ node_index,
                           const int*  __restrict__ type_index,
                           float* __restrict__ out) {
    const int b    = blockIdx.x;
    const int tid  = threadIdx.x;
    const int lane = tid & 63;
    const int w    = tid >> 6;
    const int n    = lane & 15;   // output column (h) / A row idx
    const int g    = lane >> 4;   // k-group (0..3)

    __shared__ float es[NODES];
    __shared__ float part[16][17];
    __shared__ float c0s[HID];
    __shared__ float redm[4], reds[4];

    const int t  = __builtin_amdgcn_readfirstlane(type_index[b]);
    const int ni = __builtin_amdgcn_readfirstlane(node_index[0]);

    const float* At  = a1 + (size_t)t * (2 * FDIM * HID); // top    [FDIM][HID]
    const float* Ab  = At + FDIM * HID;                   // bottom [FDIM][HID]
    const float* a2t = a2 + t * HID;
    const float* xb  = x + (size_t)b * NODES * FDIM;

    // ---- c0[h] = sum_f x[b,ni,f] * At[f][h] (cooperative, fp32) ----
    {
        const float* x0 = xb + (size_t)ni * FDIM;
        const int f2 = tid >> 4;
        const int h  = tid & 15;
        float p = 0.f;
        #pragma unroll
        for (int j = 0; j < 8; ++j) {
            const int f = f2 * 8 + j;
            p = fmaf(x0[f], At[f * HID + h], p);
        }
        part[f2][h] = p;
    }
    __syncthreads();
    if (tid < 16) {
        float s = 0.f;
        #pragma unroll
        for (int gg = 0; gg < 16; ++gg) s += part[gg][tid];
        c0s[tid] = s;
    }
    __syncthreads();

    // ---- weight B-fragments (RN bf16): lane holds Ab[k][n], k=kt*32+g*8+j --
    short8 whi[4];
    #pragma unroll
    for (int kt = 0; kt < 4; ++kt) {
        #pragma unroll
        for (int j = 0; j < 8; ++j)
            whi[kt][j] = bf_rn(Ab[(kt * 32 + g * 8 + j) * HID + n]); // L2-hot
    }

    // ---- main GEMM: 4 K-tiles x 4 M-tiles, A straight from global ----
    const int rowbase = w * 64;
    f32x4 acc[4];
    #pragma unroll
    for (int mt = 0; mt < 4; ++mt) acc[mt] = (f32x4){0.f, 0.f, 0.f, 0.f};

    #pragma unroll
    for (int kt = 0; kt < 4; ++kt) {
        #pragma unroll
        for (int mh = 0; mh < 4; mh += 2) {       // 2 M-tiles in flight
            float4 ra[2][2];
            #pragma unroll
            for (int i = 0; i < 2; ++i) {
                const float* p = xb
                    + (size_t)(rowbase + (mh + i) * 16 + n) * FDIM
                    + kt * 32 + g * 8;
                ra[i][0] = *(const float4*)p;
                ra[i][1] = *(const float4*)(p + 4);
            }
            #pragma unroll
            for (int i = 0; i < 2; ++i) {
                short8 ahi, alo;
                split8(ra[i][0], ra[i][1], ahi, alo);
                acc[mh + i] = __builtin_amdgcn_mfma_f32_16x16x32_bf16(
                    ahi, whi[kt], acc[mh + i], 0, 0, 0);
                acc[mh + i] = __builtin_amdgcn_mfma_f32_16x16x32_bf16(
                    alo, whi[kt], acc[mh + i], 0, 0, 0);
            }
        }
    }

    // ---- epilogue: e[row] = lrelu( sum_h lrelu(acc+c0[h]) * a2[h] ) ----
    const float c0h = c0s[n];
    const float a2h = a2t[n];
    #pragma unroll
    for (int mt = 0; mt < 4; ++mt) {
        #pragma unroll
        for (int r = 0; r < 4; ++r) {
            float v = acc[mt][r] + c0h;
            v = (v > 0.f) ? v : 0.01f * v;
            float s = v * a2h;
            s += __shfl_xor(s, 1);
            s += __shfl_xor(s, 2);
            s += __shfl_xor(s, 4);
            s += __shfl_xor(s, 8);      // sum over 16 h-lanes
            float e = (s > 0.f) ? s : 0.01f * s;
            if (n == 0) es[rowbase + mt * 16 + g * 4 + r] = e;
        }
    }
    __syncthreads();

    // ---- masked softmax over 256 nodes ----
    const float ee  = es[tid];
    const float m   = adj[tid];
    float       val = (m > 0.f) ? ee : -INFINITY;

    float mx = val;
    #pragma unroll
    for (int off = 32; off; off >>= 1) mx = fmaxf(mx, __shfl_xor(mx, off));
    const int wid = tid >> 6;
    if ((tid & 63) == 0) redm[wid] = mx;
    __syncthreads();
    mx = fmaxf(fmaxf(redm[0], redm[1]), fmaxf(redm[2], redm[3]));

    float pr = (m > 0.f) ? __expf(ee - mx) : 0.f;
    float s = pr;
    #pragma unroll
    for (int off = 32; off; off >>= 1) s += __shfl_xor(s, off);
    if ((tid & 63) == 0) reds[wid] = s;
    __syncthreads();
    const float Z = reds[0] + reds[1] + reds[2] + reds[3];

    out[(size_t)b * NODES + tid] = pr / Z;
}

extern "C" void kernel_launch(void* const* d_in, const int* in_sizes, int n_in,
                              void* d_out, int out_size, void* d_ws, size_t ws_size,
                              hipStream_t stream) {
    const float* x   = (const float*)d_in[0];
    const float* a1  = (const float*)d_in[1];
    const float* a2  = (const float*)d_in[2];
    const float* adj = (const float*)d_in[3];
    const int*   ni  = (const int*)d_in[4];
    const int*   ti  = (const int*)d_in[5];
    float* out = (float*)d_out;

    mta_kernel<<<BATCH, NODES, 0, stream>>>(x, a1, a2, adj, ni, ti, out);
}